// Round 5
// baseline (285.761 us; speedup 1.0000x reference)
//
#include <hip/hip_runtime.h>
#include <hip/hip_cooperative_groups.h>

namespace cg = cooperative_groups;

// KAN layer: out[b,o] = sum_i [ sum_g w[o,i,g]*exp(-|tanh(x[b,i])-grid[g]|*s[o,i])
//                               + ba[o,i]*tanh(x[b,i]) ]
// Factorization: exp(-s|xn-g|) = exp(-s*xn)*[w*e^{s*g}]   (g <= xn)
//                              = exp(+s*xn)*[w*e^{-s*g}]  (g >  xn)
// Prefix/suffix tables per (o,i) over the 5 split points k (xn in (-1,1) =>
// k in [2,6]); per (b,o,i): 2 exp2 + 3 fma + one LDS-cached 8B read.
// R5: single cooperative kernel (prep | grid.sync | main | grid.sync | reduce)
// to eliminate inter-dispatch gaps — the counters show the timed window is
// dominated by harness poison-fills (40 us) + per-op overheads, not compute.

#define B_   256
#define OUT_ 256
#define IN_  256
#define G_   8
#define NK   5           // k' = k-2
#define BG   32          // b's per main-phase block
#define ICH  16          // i's per chunk (split-K)
#define NIC  (IN_/ICH)   // 16 chunks
#define OT   64          // o-tile = one wave width

__global__ __launch_bounds__(256, 2) void kan_fused(
        const float* __restrict__ x,
        const float* __restrict__ w,
        const float* __restrict__ sc,
        const float* __restrict__ ba,
        const float* __restrict__ grd,
        float2* __restrict__ xnk,
        float2* __restrict__ sbt,
        float2* __restrict__ T,
        float*  __restrict__ partial,
        float*  __restrict__ out)
{
    cg::grid_group gg = cg::this_grid();
    const int blk = blockIdx.x;          // 0..511

    __shared__ float2 sT[NK * ICH * OT]; // 40 KB  [k][ii][o]
    __shared__ float2 sSB[ICH * OT];     // 8 KB   [ii][o] = (c, ba)
    __shared__ float2 sXK[BG * ICH];     // 4 KB   [bb][ii] = (xn, slab offset)

    // ---------------- phase 1: prep ----------------
    {
        float g[G_];
#pragma unroll
        for (int j = 0; j < G_; ++j) g[j] = grd[j];    // uniform broadcast

        if (blk < 256) {
            // part A: one (b,i) per thread, i fast -> coalesced
            const int idx = blk * 256 + threadIdx.x;
            const float xn = tanhf(x[idx]);
            int k = 0;
#pragma unroll
            for (int j = 0; j < G_; ++j) k += (g[j] <= xn) ? 1 : 0;
            k = min(max(k, 2), 6) - 2;                 // 0..4
            xnk[idx] = make_float2(xn, (float)k);
        } else {
            // part B: one i per block, o = tid -> all stores coalesced
            const int i = blk - 256;
            const int o = threadIdx.x;
            const int base = o * IN_ + i;              // strided read (L2)
            const float s  = sc[base];
            const float bv = ba[base];

            float Ep[G_], Em[G_];
#pragma unroll
            for (int j = 0; j < G_; ++j) {
                const float wv = w[base * G_ + j];
                const float t  = s * g[j];
                Ep[j] = wv * __expf(t);
                Em[j] = wv * __expf(-t);
            }
#pragma unroll
            for (int kk = 0; kk < NK; ++kk) {
                const int k = kk + 2;
                float A = 0.f, Bv = 0.f;
#pragma unroll
                for (int j = 0; j < G_; ++j) {
                    if (j < k) A += Ep[j]; else Bv += Em[j];  // static split
                }
                T[(kk * IN_ + i) * OUT_ + o] = make_float2(A, Bv); // 512B/wave
            }
            sbt[i * OUT_ + o] = make_float2(s * 1.44269504088896340736f, bv);
        }
    }

    __threadfence();
    gg.sync();

    // ---------------- phase 2: main ----------------
    {
        const int lane = threadIdx.x & 63;
        const int wv   = threadIdx.x >> 6;
        const int slab = blk & 63;        // (ot, ic) — slab-sharers same XCD
        const int bg   = blk >> 6;        // 0..7
        const int ot   = slab & 3;
        const int ic   = slab >> 2;
        const int o0   = ot * OT;
        const int i0   = ic * ICH;
        const int b0   = bg * BG;

        for (int idx = threadIdx.x; idx < NK * ICH * OT; idx += 256) {
            const int kk = idx >> 10;     // /(ICH*OT)
            const int rem = idx & 1023;
            const int ii = rem >> 6, ol = rem & 63;
            sT[idx] = T[(kk * IN_ + i0 + ii) * OUT_ + o0 + ol];   // coalesced
        }
        for (int idx = threadIdx.x; idx < ICH * OT; idx += 256) {
            const int ii = idx >> 6, ol = idx & 63;
            sSB[idx] = sbt[(i0 + ii) * OUT_ + o0 + ol];           // coalesced
        }
        for (int idx = threadIdx.x; idx < BG * ICH; idx += 256) { // 512 entries
            const int bb = idx >> 4, ii = idx & 15;
            const float2 v = xnk[(b0 + bb) * IN_ + i0 + ii];
            sXK[idx] = make_float2(v.x, __int_as_float(((int)v.y) << 10));
        }
        __syncthreads();

        float acc[8];
#pragma unroll
        for (int bb = 0; bb < 8; ++bb) acc[bb] = 0.f;

        const int wb = wv * 8;            // this wave's first b (local)
        for (int ii = 0; ii < ICH; ++ii) {
            const float2 sb = sSB[ii * OT + lane];   // 2-way bank alias: free
            const int il = ii * OT + lane;
#pragma unroll
            for (int bb = 0; bb < 8; ++bb) {
                const float2 xk = sXK[(wb + bb) * ICH + ii];       // broadcast
                const float2 rec = sT[__float_as_int(xk.y) + il];  // k-slab
                const float t = sb.x * xk.x;         // s*log2e*xn
                float a = fmaf(sb.y, xk.x, acc[bb]); // + ba*xn
                a       = fmaf(exp2f(-t), rec.x, a); // + e^{-s*xn} * A[k]
                acc[bb] = fmaf(exp2f(t),  rec.y, a); // + e^{+s*xn} * B[k]
            }
        }

        float* p = partial + ((size_t)ic * B_ + b0 + wb) * OUT_ + o0 + lane;
#pragma unroll
        for (int bb = 0; bb < 8; ++bb) p[bb * OUT_] = acc[bb];    // coalesced
    }

    __threadfence();
    gg.sync();

    // ---------------- phase 3: reduce ----------------
    if (blk < 256) {
        const int idx = blk * 256 + threadIdx.x;
        float s = 0.f;
#pragma unroll
        for (int c = 0; c < NIC; ++c) s += partial[c * (B_ * OUT_) + idx];
        out[idx] = s;                     // full overwrite of d_out
    }
}

// ---------------------------------------------------------------------------
extern "C" void kernel_launch(void* const* d_in, const int* in_sizes, int n_in,
                              void* d_out, int out_size, void* d_ws, size_t ws_size,
                              hipStream_t stream)
{
    const float* x    = (const float*)d_in[0];
    const float* w    = (const float*)d_in[1];   // (OUT, IN, G)
    const float* sc   = (const float*)d_in[2];   // (OUT, IN)
    const float* ba   = (const float*)d_in[3];   // (OUT, IN)
    const float* grd  = (const float*)d_in[4];   // (G)
    float* out = (float*)d_out;

    // ws: xnk 512KB | sbt 512KB | T 2.5MB | partial 4MB  (7.5 MB total)
    char* ws = (char*)d_ws;
    float2* xnk = (float2*)(ws);
    float2* sbt = (float2*)(ws + 512 * 1024);
    float2* T   = (float2*)(ws + 1024 * 1024);
    float*  partial = (float*)(ws + 1024 * 1024 + (size_t)NK * IN_ * OUT_ * sizeof(float2));

    void* args[] = { (void*)&x, (void*)&w, (void*)&sc, (void*)&ba, (void*)&grd,
                     (void*)&xnk, (void*)&sbt, (void*)&T, (void*)&partial,
                     (void*)&out };
    hipLaunchCooperativeKernel((void*)kan_fused, dim3(512), dim3(256),
                               args, 0, stream);
}

// Round 6
// 108.246 us; speedup vs baseline: 2.6399x; 2.6399x over previous
//
#include <hip/hip_runtime.h>

// KAN layer: out[b,o] = sum_i [ sum_g w[o,i,g]*exp(-|tanh(x[b,i])-grid[g]|*s[o,i])
//                               + ba[o,i]*tanh(x[b,i]) ]
// Factorization: exp(-s|xn-g|) = exp(-s*xn)*[w*e^{s*g}]   (g <= xn)
//                              = exp(+s*xn)*[w*e^{-s*g}]  (g >  xn)
// Prefix/suffix tables per (o,i) over the 5 split points k (xn in (-1,1) =>
// k in [2,6]); per (b,o,i): 2 exp2 + 3 fma + one 8B table read (L2-hot).
// R6: R2's proven 2-dispatch structure; BT 2->4 halves sbt traffic.
// Structural floor measured R5: ~72.6 us of harness restore/poison overhead.

#define B_   256
#define OUT_ 256
#define IN_  256
#define G_   8
#define NK   5           // k' = k-2
#define BT   4           // b's per main block (register-blocked)
#define OT   64          // o-tile = one wave width

// ---------------------------------------------------------------------------
// Kernel 1 (prep), grid 256 x 256:
//  part A: idx=(b,i) i-fast  -> xn=tanh(x), precomputed T-row. Coalesced R/W.
//  part B: i=blockIdx, o=tid -> per-(o,i) tables; stores coalesced 512B/wave
//          (T layout [k'][i][o], o fast, matching main's reads).
// ---------------------------------------------------------------------------
__global__ __launch_bounds__(256) void kan_prep(
        const float* __restrict__ x,
        const float* __restrict__ w,
        const float* __restrict__ sc,
        const float* __restrict__ ba,
        const float* __restrict__ grid,
        float2* __restrict__ xnk,
        float2* __restrict__ sbt,
        float2* __restrict__ T)
{
    float g[G_];
#pragma unroll
    for (int j = 0; j < G_; ++j) g[j] = grid[j];   // uniform broadcast loads

    // ---- part A: one (b,i) per thread, i fast -> coalesced
    {
        const int idx = blockIdx.x * 256 + threadIdx.x;
        const float xn = tanhf(x[idx]);
        int k = 0;
#pragma unroll
        for (int j = 0; j < G_; ++j) k += (g[j] <= xn) ? 1 : 0;
        k = min(max(k, 2), 6) - 2;                 // 0..4
        const int row = k * IN_ + (idx & (IN_ - 1));
        xnk[idx] = make_float2(xn, __int_as_float(row));
    }

    // ---- part B: one i per block, o = tid -> all stores coalesced
    {
        const int i = blockIdx.x;
        const int o = threadIdx.x;
        const int base = o * IN_ + i;              // strided reads (L2-hot)
        const float s  = sc[base];
        const float bv = ba[base];

        float Ep[G_], Em[G_];
#pragma unroll
        for (int j = 0; j < G_; ++j) {
            const float wv = w[base * G_ + j];
            const float t  = s * g[j];
            Ep[j] = wv * __expf(t);
            Em[j] = wv * __expf(-t);
        }
#pragma unroll
        for (int kk = 0; kk < NK; ++kk) {
            const int k = kk + 2;
            float A = 0.f, Bv = 0.f;
#pragma unroll
            for (int j = 0; j < G_; ++j) {
                if (j < k) A += Ep[j]; else Bv += Em[j];   // static split
            }
            T[(kk * IN_ + i) * OUT_ + o] = make_float2(A, Bv);  // 512B/wave
        }
        sbt[i * OUT_ + o] = make_float2(s * 1.44269504088896340736f, bv);
    }
}

// ---------------------------------------------------------------------------
// Kernel 2 (main): grid = (B/BT) x (OUT/OT) = 256 blocks, 256 threads.
// Block = 4 waves; wave ig owns i in [ig*64, ig*64+64), 64 o-lanes, BT=4 b's.
// Full i-reduction inside the block via LDS tree -> direct d_out store.
// Per (b,o,i): 1 LDS broadcast + 1 L2 8B read + 2 exp2 + 3 fma.
// ---------------------------------------------------------------------------
__global__ __launch_bounds__(256) void kan_main(
        const float2* __restrict__ xnk,
        const float2* __restrict__ sbt,
        const float2* __restrict__ T,
        float* __restrict__ out)
{
    const int lane = threadIdx.x & 63;
    const int igrp = threadIdx.x >> 6;          // 0..3
    const int ot   = blockIdx.x & 3;            // 4 o-tiles
    const int bg   = blockIdx.x >> 2;           // 64 b-groups
    const int o    = ot * OT + lane;
    const int b0   = bg * BT;

    __shared__ float2 sxk[BT * IN_];            // 8 KB: (xn, T-byte-row) per b
    __shared__ float  sacc[4][BT][OT];          // 4 KB: per-wave partials

    for (int t = threadIdx.x; t < BT * IN_; t += 256) {
        float2 v = xnk[b0 * IN_ + t];           // coalesced
        // pre-shift row*OUT_ so the hot loop does one add only
        sxk[t] = make_float2(v.x, __int_as_float(__float_as_int(v.y) << 8));
    }
    __syncthreads();

    float acc[BT];
#pragma unroll
    for (int bb = 0; bb < BT; ++bb) acc[bb] = 0.f;

    const int i0 = igrp * 64;
#pragma unroll 2
    for (int ii = 0; ii < 64; ++ii) {
        const int i = i0 + ii;
        const float2 sb = sbt[i * OUT_ + o];    // 512B/wave, L2-hot
#pragma unroll
        for (int bb = 0; bb < BT; ++bb) {
            const float2 xk = sxk[bb * IN_ + i];  // wave-uniform LDS broadcast
            const float xn  = xk.x;
            const float2 rec = T[__float_as_int(xk.y) + o]; // 512B/wave, L2
            const float t = sb.x * xn;            // s*log2e*xn
            float a = fmaf(sb.y, xn, acc[bb]);    // + ba*xn
            a       = fmaf(exp2f(-t), rec.x, a);  // + e^{-s*xn} * A[k]
            acc[bb] = fmaf(exp2f(t),  rec.y, a);  // + e^{+s*xn} * B[k]
        }
    }

#pragma unroll
    for (int bb = 0; bb < BT; ++bb) sacc[igrp][bb][lane] = acc[bb];
    __syncthreads();

    if (threadIdx.x < BT * OT) {
        const int bb = threadIdx.x >> 6;
        const int l  = threadIdx.x & 63;
        const float s = sacc[0][bb][l] + sacc[1][bb][l]
                      + sacc[2][bb][l] + sacc[3][bb][l];
        out[(b0 + bb) * OUT_ + ot * OT + l] = s;  // coalesced, full overwrite
    }
}

// ---------------------------------------------------------------------------
extern "C" void kernel_launch(void* const* d_in, const int* in_sizes, int n_in,
                              void* d_out, int out_size, void* d_ws, size_t ws_size,
                              hipStream_t stream)
{
    const float* x    = (const float*)d_in[0];
    const float* w    = (const float*)d_in[1];   // (OUT, IN, G)
    const float* sc   = (const float*)d_in[2];   // (OUT, IN)
    const float* ba   = (const float*)d_in[3];   // (OUT, IN)
    const float* grid = (const float*)d_in[4];   // (G)
    float* out = (float*)d_out;

    // ws: xnk 512KB | sbt 512KB | T 2.5MB   (3.5 MB total)
    char* ws = (char*)d_ws;
    float2* xnk = (float2*)(ws);
    float2* sbt = (float2*)(ws + 512 * 1024);
    float2* T   = (float2*)(ws + 1024 * 1024);

    kan_prep<<<IN_, 256, 0, stream>>>(x, w, sc, ba, grid, xnk, sbt, T);
    kan_main<<<(B_ / BT) * (OUT_ / OT), 256, 0, stream>>>(xnk, sbt, T, out);
}

// Round 7
// 80.508 us; speedup vs baseline: 3.5495x; 1.3445x over previous
//
#include <hip/hip_runtime.h>

// KAN layer: out[b,o] = sum_i [ sum_g w[o,i,g]*exp(-|tanh(x[b,i])-grid[g]|*s[o,i])
//                               + ba[o,i]*tanh(x[b,i]) ]
// Factorization: exp(-s|xn-g|) = exp(-s*xn)*[w*e^{s*g}]   (g <= xn)
//                              = exp(+s*xn)*[w*e^{-s*g}]  (g >  xn)
// Prefix/suffix tables per (o,i) over the 5 split points k (xn in (-1,1) =>
// k in [2,6]); per (b,o,i): 2 exp2 + 3 fma + one 8B table read (L2-hot).
//
// R7: main loop is L2-LATENCY-bound (R6: 1 wave/SIMD -> 42.6us, serialized
// ~400cyc/iter). Fix = occupancy: 512 blocks x 512 threads (8 waves/block,
// 2 blocks/CU, 4 waves/SIMD) + unroll-4 ILP. BT=2 (R6's BT=4 grid-halving
// was the regression). Structural harness floor measured R5: ~72.6 us.

#define B_   256
#define OUT_ 256
#define IN_  256
#define G_   8
#define NK   5           // k' = k-2
#define BT   2           // b's per main block (register-blocked)
#define OT   64          // o-tile = one wave width
#define NW   8           // waves per main block
#define IW   (IN_/NW)    // 32 i's per wave

// ---------------------------------------------------------------------------
// Kernel 1 (prep), grid 256 x 256:
//  part A: idx=(b,i) i-fast  -> xn=tanh(x), precomputed T-row. Coalesced R/W.
//  part B: i=blockIdx, o=tid -> per-(o,i) tables; stores coalesced 512B/wave
//          (T layout [k'][i][o], o fast, matching main's reads).
// ---------------------------------------------------------------------------
__global__ __launch_bounds__(256) void kan_prep(
        const float* __restrict__ x,
        const float* __restrict__ w,
        const float* __restrict__ sc,
        const float* __restrict__ ba,
        const float* __restrict__ grid,
        float2* __restrict__ xnk,
        float2* __restrict__ sbt,
        float2* __restrict__ T)
{
    float g[G_];
#pragma unroll
    for (int j = 0; j < G_; ++j) g[j] = grid[j];   // uniform broadcast loads

    // ---- part A: one (b,i) per thread, i fast -> coalesced
    {
        const int idx = blockIdx.x * 256 + threadIdx.x;
        const float xn = tanhf(x[idx]);
        int k = 0;
#pragma unroll
        for (int j = 0; j < G_; ++j) k += (g[j] <= xn) ? 1 : 0;
        k = min(max(k, 2), 6) - 2;                 // 0..4
        const int row = k * IN_ + (idx & (IN_ - 1));
        xnk[idx] = make_float2(xn, __int_as_float(row));
    }

    // ---- part B: one i per block, o = tid -> all stores coalesced
    {
        const int i = blockIdx.x;
        const int o = threadIdx.x;
        const int base = o * IN_ + i;              // strided reads (L2-hot)
        const float s  = sc[base];
        const float bv = ba[base];

        float Ep[G_], Em[G_];
#pragma unroll
        for (int j = 0; j < G_; ++j) {
            const float wv = w[base * G_ + j];
            const float t  = s * g[j];
            Ep[j] = wv * __expf(t);
            Em[j] = wv * __expf(-t);
        }
#pragma unroll
        for (int kk = 0; kk < NK; ++kk) {
            const int k = kk + 2;
            float A = 0.f, Bv = 0.f;
#pragma unroll
            for (int j = 0; j < G_; ++j) {
                if (j < k) A += Ep[j]; else Bv += Em[j];   // static split
            }
            T[(kk * IN_ + i) * OUT_ + o] = make_float2(A, Bv);  // 512B/wave
        }
        sbt[i * OUT_ + o] = make_float2(s * 1.44269504088896340736f, bv);
    }
}

// ---------------------------------------------------------------------------
// Kernel 2 (main): grid = (B/BT)=128 b-groups x 4 o-tiles = 512 blocks,
// 512 threads = 8 waves (2 blocks/CU -> 4 waves/SIMD). Wave ig owns 32 i's,
// 64 o-lanes, BT=2 b's. Full i-reduction via LDS tree -> direct d_out store.
// Per (b,o,i): 1 LDS broadcast + 1 L2 8B read + 2 exp2 + 3 fma.
// ---------------------------------------------------------------------------
__global__ __launch_bounds__(512, 4) void kan_main(
        const float2* __restrict__ xnk,
        const float2* __restrict__ sbt,
        const float2* __restrict__ T,
        float* __restrict__ out)
{
    const int lane = threadIdx.x & 63;
    const int igrp = threadIdx.x >> 6;          // 0..7
    const int ot   = blockIdx.x & 3;            // 4 o-tiles
    const int bg   = blockIdx.x >> 2;           // 128 b-groups
    const int o    = ot * OT + lane;
    const int b0   = bg * BT;

    __shared__ float2 sxk[BT * IN_];            // 4 KB: (xn, T-byte-row) per b
    __shared__ float  sacc[NW][BT][OT];         // 4 KB: per-wave partials

    for (int t = threadIdx.x; t < BT * IN_; t += 512) {
        float2 v = xnk[b0 * IN_ + t];           // coalesced
        // pre-shift row*OUT_ so the hot loop does one add only
        sxk[t] = make_float2(v.x, __int_as_float(__float_as_int(v.y) << 8));
    }
    __syncthreads();

    float acc[BT];
#pragma unroll
    for (int bb = 0; bb < BT; ++bb) acc[bb] = 0.f;

    const int i0 = igrp * IW;
#pragma unroll 4
    for (int ii = 0; ii < IW; ++ii) {
        const int i = i0 + ii;
        const float2 sb = sbt[i * OUT_ + o];    // 512B/wave, L2-hot
#pragma unroll
        for (int bb = 0; bb < BT; ++bb) {
            const float2 xk = sxk[bb * IN_ + i];  // wave-uniform LDS broadcast
            const float xn  = xk.x;
            const float2 rec = T[__float_as_int(xk.y) + o]; // 512B/wave, L2
            const float t = sb.x * xn;            // s*log2e*xn
            float a = fmaf(sb.y, xn, acc[bb]);    // + ba*xn
            a       = fmaf(exp2f(-t), rec.x, a);  // + e^{-s*xn} * A[k]
            acc[bb] = fmaf(exp2f(t),  rec.y, a);  // + e^{+s*xn} * B[k]
        }
    }

#pragma unroll
    for (int bb = 0; bb < BT; ++bb) sacc[igrp][bb][lane] = acc[bb];
    __syncthreads();

    if (threadIdx.x < BT * OT) {
        const int bb = threadIdx.x >> 6;
        const int l  = threadIdx.x & 63;
        float s = 0.f;
#pragma unroll
        for (int wv = 0; wv < NW; ++wv) s += sacc[wv][bb][l];
        out[(b0 + bb) * OUT_ + ot * OT + l] = s;  // coalesced, full overwrite
    }
}

// ---------------------------------------------------------------------------
extern "C" void kernel_launch(void* const* d_in, const int* in_sizes, int n_in,
                              void* d_out, int out_size, void* d_ws, size_t ws_size,
                              hipStream_t stream)
{
    const float* x    = (const float*)d_in[0];
    const float* w    = (const float*)d_in[1];   // (OUT, IN, G)
    const float* sc   = (const float*)d_in[2];   // (OUT, IN)
    const float* ba   = (const float*)d_in[3];   // (OUT, IN)
    const float* grid = (const float*)d_in[4];   // (G)
    float* out = (float*)d_out;

    // ws: xnk 512KB | sbt 512KB | T 2.5MB   (3.5 MB total)
    char* ws = (char*)d_ws;
    float2* xnk = (float2*)(ws);
    float2* sbt = (float2*)(ws + 512 * 1024);
    float2* T   = (float2*)(ws + 1024 * 1024);

    kan_prep<<<IN_, 256, 0, stream>>>(x, w, sc, ba, grid, xnk, sbt, T);
    kan_main<<<(B_ / BT) * (OUT_ / OT), 512, 0, stream>>>(xnk, sbt, T, out);
}